// Round 17
// baseline (316.901 us; speedup 1.0000x reference)
//
#include <hip/hip_runtime.h>
#include <cstddef>
#include <cstdint>

constexpr int B = 4, S = 2048, E = 1024, H = 16, D = 64;
constexpr int M_ROWS = B * S;   // 8192
constexpr float LOG2E = 1.4426950408889634f;

typedef __bf16 bf16x8 __attribute__((ext_vector_type(8)));
typedef float  f32x4  __attribute__((ext_vector_type(4)));

__device__ __forceinline__ unsigned short f2bf(float x) {
    union { float f; uint32_t u; } v; v.f = x;
    uint32_t r = v.u + 0x7fff + ((v.u >> 16) & 1);   // RNE
    return (unsigned short)(r >> 16);
}
__device__ __forceinline__ unsigned short f2bf_fast(float x) {
    return __builtin_bit_cast(unsigned short, (__bf16)x);   // native cvt (1 instr)
}
__device__ __forceinline__ void gld_lds16(const unsigned short* g, unsigned short* l) {
    __builtin_amdgcn_global_load_lds(
        (const __attribute__((address_space(1))) void*)g,
        (__attribute__((address_space(3))) void*)l, 16, 0, 0);
}
__device__ __forceinline__ void drain_publish() {
    asm volatile("s_waitcnt vmcnt(0)" ::: "memory");
    __builtin_amdgcn_sched_barrier(0);
    __syncthreads();
}

// ---------------------------------------------------------------------------
// fp32 -> bf16 (hi only): x (4096 blks), w1 (1536), w2 (512); 8 elems/thread.
// ---------------------------------------------------------------------------
__global__ __launch_bounds__(256)
void cvt_bf16(const float* __restrict__ x,  unsigned short* __restrict__ xb,
              const float* __restrict__ w1, unsigned short* __restrict__ w1b,
              const float* __restrict__ w2, unsigned short* __restrict__ w2b)
{
    const int bid = blockIdx.x;
    const float* s; unsigned short* d; size_t idx;
    if (bid < 4096)      { s = x;  d = xb;  idx = (size_t)bid * 256 + threadIdx.x; }
    else if (bid < 5632) { s = w1; d = w1b; idx = (size_t)(bid - 4096) * 256 + threadIdx.x; }
    else                 { s = w2; d = w2b; idx = (size_t)(bid - 5632) * 256 + threadIdx.x; }
    const float4* s4 = (const float4*)s;
    float4 v0 = s4[idx * 2], v1 = s4[idx * 2 + 1];
    float f[8] = { v0.x, v0.y, v0.z, v0.w, v1.x, v1.y, v1.z, v1.w };
    unsigned short hh[8];
    #pragma unroll
    for (int j = 0; j < 8; ++j) hh[j] = f2bf(f[j]);
    ((int4*)d)[idx] = *(const int4*)hh;
}

// ---------------------------------------------------------------------------
// Plain bf16 MFMA GEMM (R12/R13-proven): C[M,N] = A[M,KD] @ W[N,KD]^T + bias
// 128x128 tile, BK=32, 256 thr = 4 waves, 32KB LDS (2 bufs), double-buffered
// global_load_lds with explicit vmcnt(0)+sched_barrier drain (race-safe).
// MODE 0: C fp32 [M,N] + bias
// MODE 1: q (pre-scaled by 0.125*log2e), k -> bf16 [B,H,S,D] direct;
//         v -> bf16 [B,H,D,S] via wave-private LDS repack.
// ---------------------------------------------------------------------------
template<int MODE, int KD>
__global__ __launch_bounds__(256)
void gemm_bf16(const unsigned short* __restrict__ A, const unsigned short* __restrict__ W,
               const float* __restrict__ bias, float* __restrict__ C,
               unsigned short* __restrict__ qd, unsigned short* __restrict__ kd,
               unsigned short* __restrict__ vd, int M, int N)
{
    __shared__ __align__(16) unsigned short lds[2][2][128 * 32];  // [buf][A/W]

    const int t    = threadIdx.x;
    const int wid  = t >> 6, lane = t & 63;
    const int l16  = lane & 15, lg = lane >> 4;
    const int wr   = wid >> 1, wc = wid & 1;
    const int m0   = blockIdx.y * 128;
    const int n0   = blockIdx.x * 128;

    const unsigned short* ga = A + (size_t)m0 * KD;
    const unsigned short* gw = W + (size_t)n0 * KD;

    int srow[2], soff[2];
    #pragma unroll
    for (int half = 0; half < 2; ++half) {
        int c   = half * 256 + t;
        int row = c >> 2, cc = c & 3;
        srow[half] = row;
        soff[half] = (cc ^ ((row >> 1) & 3)) * 8;
    }

    f32x4 acc[4][4];
    #pragma unroll
    for (int mi = 0; mi < 4; ++mi)
        #pragma unroll
        for (int ni = 0; ni < 4; ++ni) acc[mi][ni] = (f32x4){0.f, 0.f, 0.f, 0.f};

    auto stage = [&](int k0, int buf) {
        #pragma unroll
        for (int half = 0; half < 2; ++half) {
            unsigned short* la = &lds[buf][0][(half * 256 + wid * 64) * 8];
            unsigned short* lw = &lds[buf][1][(half * 256 + wid * 64) * 8];
            gld_lds16(ga + (size_t)srow[half] * KD + k0 + soff[half], la);
            gld_lds16(gw + (size_t)srow[half] * KD + k0 + soff[half], lw);
        }
    };

    stage(0, 0);
    drain_publish();

    constexpr int NIT = KD / 32;
    for (int it = 0; it < NIT; ++it) {
        const int cur = it & 1;
        if (it + 1 < NIT) stage((it + 1) * 32, cur ^ 1);

        bf16x8 a[4], b[4];
        #pragma unroll
        for (int mi = 0; mi < 4; ++mi) {
            int arow = wr * 64 + mi * 16 + l16;
            a[mi] = *(const bf16x8*)&lds[cur][0][arow * 32 + ((lg ^ ((arow >> 1) & 3)) << 3)];
        }
        #pragma unroll
        for (int ni = 0; ni < 4; ++ni) {
            int brow = wc * 64 + ni * 16 + l16;
            b[ni] = *(const bf16x8*)&lds[cur][1][brow * 32 + ((lg ^ ((brow >> 1) & 3)) << 3)];
        }
        #pragma unroll
        for (int mi = 0; mi < 4; ++mi)
            #pragma unroll
            for (int ni = 0; ni < 4; ++ni)
                acc[mi][ni] = __builtin_amdgcn_mfma_f32_16x16x32_bf16(a[mi], b[ni], acc[mi][ni], 0, 0, 0);

        drain_publish();
    }

    const int colblk = n0 + wc * 64;
    if constexpr (MODE == 0) {
        #pragma unroll
        for (int mi = 0; mi < 4; ++mi)
            #pragma unroll
            for (int r = 0; r < 4; ++r) {
                int row = m0 + wr * 64 + mi * 16 + lg * 4 + r;
                #pragma unroll
                for (int ni = 0; ni < 4; ++ni) {
                    int col = colblk + ni * 16 + l16;
                    C[(size_t)row * N + col] = acc[mi][ni][r] + bias[col];
                }
            }
    } else {
        const int which = colblk >> 10;            // 0:q 1:k 2:v (uniform per wave)
        const int e0    = colblk & (E - 1);
        const int h_    = e0 >> 6;
        const int rowg0 = m0 + wr * 64;
        const int b_    = rowg0 >> 11;
        const int s0g   = rowg0 & (S - 1);

        if (which < 2) {
            unsigned short* dst = (which == 0) ? qd : kd;
            const float osc = (which == 0) ? 0.125f * LOG2E : 1.0f;   // fold scale into q
            #pragma unroll
            for (int mi = 0; mi < 4; ++mi)
                #pragma unroll
                for (int r = 0; r < 4; ++r) {
                    int s_ = s0g + mi * 16 + lg * 4 + r;
                    #pragma unroll
                    for (int ni = 0; ni < 4; ++ni) {
                        int col = colblk + ni * 16 + l16;
                        int d_  = col & 63;
                        dst[(((size_t)(b_ * H + h_)) * S + s_) * D + d_] =
                            f2bf((acc[mi][ni][r] + bias[col]) * osc);
                    }
                }
        } else {
            // v: wave-private 4KB repack (2 passes of [32 d][64 s]) -> int4 stores
            unsigned short* et = &lds[0][0][0] + wid * 2048;
            #pragma unroll
            for (int p = 0; p < 2; ++p) {
                #pragma unroll
                for (int nj = 0; nj < 2; ++nj) {
                    int ni   = p * 2 + nj;
                    int dloc = nj * 16 + l16;              // 0..31
                    float bv = bias[colblk + ni * 16 + l16];
                    #pragma unroll
                    for (int mi = 0; mi < 4; ++mi)
                        #pragma unroll
                        for (int r = 0; r < 4; ++r) {
                            int s = mi * 16 + lg * 4 + r;
                            et[dloc * 64 + (((s >> 3) ^ (dloc & 7)) << 3) + (s & 7)] =
                                f2bf(acc[mi][ni][r] + bv);
                        }
                }
                #pragma unroll
                for (int it = 0; it < 4; ++it) {
                    int c  = it * 64 + lane;
                    int dd = c >> 3, j8 = c & 7;
                    int4 vv = *(const int4*)&et[dd * 64 + ((j8 ^ (dd & 7)) << 3)];
                    *(int4*)&vd[(((size_t)(b_ * H + h_)) * D + p * 32 + dd) * S + s0g + j8 * 8] = vv;
                }
            }
        }
    }
}

// ---------------------------------------------------------------------------
// MFMA flash attention, softmax-without-max, SWAPPED QK^T (R13 base):
// QK^T computed as mfma(K, Q): lane holds scores for ONE q-row (q=l16) and
// 4 consecutive keys (k = kt*16 + lg*4 + r). Softmax per lane becomes:
//   - rel: ONE float4 load per kt (was 16 scalar loads)
//   - P:   ONE 8B uint2 LDS write per kt (was 16 scalar writes), same
//          XOR-swizzled layout so the PV read side is unchanged
//   - l:   single scalar per lane; shfl_xor(16,32) reduce after the loop,
//          4 __shfl in the epilogue to fetch the row sums.
// K/V staging, PV, LDS sizes (24KB), sync structure identical to R13.
// ---------------------------------------------------------------------------
__global__ __launch_bounds__(256)
void attn_mfma(const unsigned short* __restrict__ Qb,
               const unsigned short* __restrict__ Kb,
               const unsigned short* __restrict__ Vtb,
               const float* __restrict__ rel,
               unsigned short* __restrict__ AOb)
{
    __shared__ unsigned short lds_k[4096];      // K  [64 k][64 d] swz (8KB)
    __shared__ unsigned short lds_v[4096];      // Vt [64 d][64 k] swz (8KB)
    __shared__ unsigned short lds_p[4][1024];   // per-wave P [16 q][64 k] swz (8KB)

    const int t    = threadIdx.x;
    const int wid  = t >> 6, lane = t & 63;
    const int l16  = lane & 15, lg = lane >> 4;
    const int bh   = blockIdx.y;
    const int q0   = blockIdx.x * 64;
    const int b_   = bh >> 4, h_ = bh & 15;

    const size_t qkoff = (size_t)bh * S * D;
    const size_t vtoff = (size_t)bh * D * S;

    bf16x8 qf[2];   // pre-scaled by 0.125*log2e in gemm_bf16<1>
    {
        const unsigned short* qrow = Qb + qkoff + (size_t)(q0 + wid * 16 + l16) * D;
        qf[0] = *(const bf16x8*)(qrow + lg * 8);
        qf[1] = *(const bf16x8*)(qrow + 32 + lg * 8);
    }

    const float* relrow = rel + (size_t)(q0 + wid * 16 + l16) * S;

    float l_run = 0.f;
    f32x4 o[4];
    #pragma unroll
    for (int dt = 0; dt < 4; ++dt) o[dt] = (f32x4){0.f, 0.f, 0.f, 0.f};

    for (int k0 = 0; k0 < S; k0 += 64) {
        __syncthreads();
        #pragma unroll
        for (int i = 0; i < 2; ++i) {
            int c   = wid * 128 + i * 64 + lane;
            int row = c >> 3, cc = c & 7;
            int sc  = cc ^ (row & 7);
            const unsigned short* gk = Kb  + qkoff + (size_t)(k0 + row) * D + sc * 8;
            *(int4*)&lds_k[c * 8] = *(const int4*)gk;
            const unsigned short* gv = Vtb + vtoff + (size_t)row * S + k0 + sc * 8;
            *(int4*)&lds_v[c * 8] = *(const int4*)gv;
        }
        __syncthreads();

        // ---- QK^T, SWAPPED: acc[kt][r] = score[q = l16][k = kt*16+lg*4+r] ----
        f32x4 acc[4];
        #pragma unroll
        for (int kt = 0; kt < 4; ++kt) acc[kt] = (f32x4){0.f, 0.f, 0.f, 0.f};
        #pragma unroll
        for (int f = 0; f < 2; ++f) {
            #pragma unroll
            for (int kt = 0; kt < 4; ++kt) {
                int key   = kt * 16 + l16;
                int chunk = (f * 4 + lg) ^ (key & 7);
                bf16x8 kf = *(const bf16x8*)&lds_k[key * 64 + chunk * 8];
                acc[kt] = __builtin_amdgcn_mfma_f32_16x16x32_bf16(kf, qf[f], acc[kt], 0, 0, 0);
            }
        }

        // ---- p = exp2(qk2 + rel*log2e): 1 float4 rel load + 1 uint2 P write
        //      per kt; l accumulates into a single per-lane scalar ----
        unsigned short* pw = &lds_p[wid][0];
        #pragma unroll
        for (int kt = 0; kt < 4; ++kt) {
            float4 rl = *(const float4*)(relrow + k0 + kt * 16 + lg * 4);
            const float* rlp = (const float*)&rl;
            unsigned short pk[4];
            #pragma unroll
            for (int r = 0; r < 4; ++r) {
                float pv = __builtin_amdgcn_exp2f(fmaf(rlp[r], LOG2E, acc[kt][r]));
                l_run += pv;
                pk[r] = f2bf_fast(pv);
            }
            // P[q=l16][k=kt*16+lg*4 ..+3]: chunk 2kt+(lg>>1), half (lg&1), XOR swz
            *(uint2*)&pw[l16 * 64 + (((2 * kt + (lg >> 1)) ^ (l16 & 7)) << 3)
                         + ((lg & 1) << 2)] = *(const uint2*)pk;
        }

        // ---- PV (unchanged: P layout in LDS identical to before) ----
        #pragma unroll
        for (int f = 0; f < 2; ++f) {
            int pchunk = (f * 4 + lg) ^ (l16 & 7);
            bf16x8 pf = *(const bf16x8*)&pw[l16 * 64 + pchunk * 8];
            #pragma unroll
            for (int dt = 0; dt < 4; ++dt) {
                int d      = dt * 16 + l16;
                int vchunk = (f * 4 + lg) ^ (d & 7);
                bf16x8 vf  = *(const bf16x8*)&lds_v[d * 64 + vchunk * 8];
                o[dt] = __builtin_amdgcn_mfma_f32_16x16x32_bf16(pf, vf, o[dt], 0, 0, 0);
            }
        }
    }

    // reduce l across the 4 lanes sharing l16 (q-row), then fetch per-row sums
    l_run += __shfl_xor(l_run, 16);
    l_run += __shfl_xor(l_run, 32);

    #pragma unroll
    for (int r = 0; r < 4; ++r) {
        float inv = 1.f / __shfl(l_run, lg * 4 + r);   // lane (lg*4+r) holds row lg*4+r
        int qr = q0 + wid * 16 + lg * 4 + r;
        size_t base = ((size_t)b_ * S + qr) * E + h_ * 64;
        #pragma unroll
        for (int dt = 0; dt < 4; ++dt)
            AOb[base + dt * 16 + l16] = f2bf(o[dt][r] * inv);
    }
}

// ---------------------------------------------------------------------------
extern "C" void kernel_launch(void* const* d_in, const int* in_sizes, int n_in,
                              void* d_out, int out_size, void* d_ws, size_t ws_size,
                              hipStream_t stream)
{
    const float* x   = (const float*)d_in[0];
    const float* w1  = (const float*)d_in[1];
    const float* b1  = (const float*)d_in[2];
    const float* w2  = (const float*)d_in[3];
    const float* b2  = (const float*)d_in[4];
    const float* rel = (const float*)d_in[5];
    float* out = (float*)d_out;

    // workspace (ushort), ~76 MiB; AO reuses the xb region (serial stream)
    unsigned short* p = (unsigned short*)d_ws;
    unsigned short* xb  = p;  p += (size_t)M_ROWS * E;    // 16 MiB [8192][1024]
    unsigned short* w1b = p;  p += (size_t)3 * E * E;     //  6 MiB [3072][1024]
    unsigned short* w2b = p;  p += (size_t)E * E;         //  2 MiB [1024][1024]
    unsigned short* qb  = p;  p += (size_t)B * H * S * D; // 16 MiB [B,H,S,D]
    unsigned short* kb  = p;  p += (size_t)B * H * S * D; // 16 MiB [B,H,S,D]
    unsigned short* vb  = p;                              // 16 MiB [B,H,D,S]
    unsigned short* AOb = xb;                             // reuse after gemm<1>

    cvt_bf16<<<dim3(6144), dim3(256), 0, stream>>>(x, xb, w1, w1b, w2, w2b);

    dim3 g1(3 * E / 128, M_ROWS / 128);
    gemm_bf16<1, 1024><<<g1, dim3(256), 0, stream>>>(xb, w1b, b1, nullptr,
                                                     qb, kb, vb, M_ROWS, 3 * E);

    dim3 g2(S / 64, B * H);
    attn_mfma<<<g2, dim3(256), 0, stream>>>(qb, kb, vb, rel, AOb);

    dim3 g3(E / 128, M_ROWS / 128);
    gemm_bf16<0, 1024><<<g3, dim3(256), 0, stream>>>(AOb, w2b, b2, out,
                                                     nullptr, nullptr, nullptr, M_ROWS, E);
}

// Round 18
// 248.815 us; speedup vs baseline: 1.2736x; 1.2736x over previous
//
#include <hip/hip_runtime.h>
#include <cstddef>
#include <cstdint>

constexpr int B = 4, S = 2048, E = 1024, H = 16, D = 64;
constexpr int M_ROWS = B * S;   // 8192
constexpr float LOG2E = 1.4426950408889634f;

typedef __bf16 bf16x8 __attribute__((ext_vector_type(8)));
typedef float  f32x4  __attribute__((ext_vector_type(4)));

__device__ __forceinline__ unsigned short f2bf(float x) {
    union { float f; uint32_t u; } v; v.f = x;
    uint32_t r = v.u + 0x7fff + ((v.u >> 16) & 1);   // RNE
    return (unsigned short)(r >> 16);
}
__device__ __forceinline__ unsigned short f2bf_fast(float x) {
    return __builtin_bit_cast(unsigned short, (__bf16)x);   // native cvt (1 instr)
}
__device__ __forceinline__ void gld_lds16(const unsigned short* g, unsigned short* l) {
    __builtin_amdgcn_global_load_lds(
        (const __attribute__((address_space(1))) void*)g,
        (__attribute__((address_space(3))) void*)l, 16, 0, 0);
}
__device__ __forceinline__ void drain_publish() {
    asm volatile("s_waitcnt vmcnt(0)" ::: "memory");
    __builtin_amdgcn_sched_barrier(0);
    __syncthreads();
}

// ---------------------------------------------------------------------------
// fp32 -> bf16 (hi only): x (4096 blks), w1 (1536), w2 (512); 8 elems/thread.
// ---------------------------------------------------------------------------
__global__ __launch_bounds__(256)
void cvt_bf16(const float* __restrict__ x,  unsigned short* __restrict__ xb,
              const float* __restrict__ w1, unsigned short* __restrict__ w1b,
              const float* __restrict__ w2, unsigned short* __restrict__ w2b)
{
    const int bid = blockIdx.x;
    const float* s; unsigned short* d; size_t idx;
    if (bid < 4096)      { s = x;  d = xb;  idx = (size_t)bid * 256 + threadIdx.x; }
    else if (bid < 5632) { s = w1; d = w1b; idx = (size_t)(bid - 4096) * 256 + threadIdx.x; }
    else                 { s = w2; d = w2b; idx = (size_t)(bid - 5632) * 256 + threadIdx.x; }
    const float4* s4 = (const float4*)s;
    float4 v0 = s4[idx * 2], v1 = s4[idx * 2 + 1];
    float f[8] = { v0.x, v0.y, v0.z, v0.w, v1.x, v1.y, v1.z, v1.w };
    unsigned short hh[8];
    #pragma unroll
    for (int j = 0; j < 8; ++j) hh[j] = f2bf(f[j]);
    ((int4*)d)[idx] = *(const int4*)hh;
}

// ---------------------------------------------------------------------------
// Plain bf16 MFMA GEMM (R12/R13-proven): C[M,N] = A[M,KD] @ W[N,KD]^T + bias
// 128x128 tile, BK=32, 256 thr = 4 waves, 32KB LDS (2 bufs), double-buffered
// global_load_lds with explicit vmcnt(0)+sched_barrier drain (race-safe).
// MODE 0: C fp32 [M,N] + bias
// MODE 1: q (pre-scaled by 0.125*log2e), k -> bf16 [B,H,S,D] direct;
//         v -> bf16 [B,H,D,S] via wave-private LDS repack.
// ---------------------------------------------------------------------------
template<int MODE, int KD>
__global__ __launch_bounds__(256)
void gemm_bf16(const unsigned short* __restrict__ A, const unsigned short* __restrict__ W,
               const float* __restrict__ bias, float* __restrict__ C,
               unsigned short* __restrict__ qd, unsigned short* __restrict__ kd,
               unsigned short* __restrict__ vd, int M, int N)
{
    __shared__ __align__(16) unsigned short lds[2][2][128 * 32];  // [buf][A/W]

    const int t    = threadIdx.x;
    const int wid  = t >> 6, lane = t & 63;
    const int l16  = lane & 15, lg = lane >> 4;
    const int wr   = wid >> 1, wc = wid & 1;
    const int m0   = blockIdx.y * 128;
    const int n0   = blockIdx.x * 128;

    const unsigned short* ga = A + (size_t)m0 * KD;
    const unsigned short* gw = W + (size_t)n0 * KD;

    int srow[2], soff[2];
    #pragma unroll
    for (int half = 0; half < 2; ++half) {
        int c   = half * 256 + t;
        int row = c >> 2, cc = c & 3;
        srow[half] = row;
        soff[half] = (cc ^ ((row >> 1) & 3)) * 8;
    }

    f32x4 acc[4][4];
    #pragma unroll
    for (int mi = 0; mi < 4; ++mi)
        #pragma unroll
        for (int ni = 0; ni < 4; ++ni) acc[mi][ni] = (f32x4){0.f, 0.f, 0.f, 0.f};

    auto stage = [&](int k0, int buf) {
        #pragma unroll
        for (int half = 0; half < 2; ++half) {
            unsigned short* la = &lds[buf][0][(half * 256 + wid * 64) * 8];
            unsigned short* lw = &lds[buf][1][(half * 256 + wid * 64) * 8];
            gld_lds16(ga + (size_t)srow[half] * KD + k0 + soff[half], la);
            gld_lds16(gw + (size_t)srow[half] * KD + k0 + soff[half], lw);
        }
    };

    stage(0, 0);
    drain_publish();

    constexpr int NIT = KD / 32;
    for (int it = 0; it < NIT; ++it) {
        const int cur = it & 1;
        if (it + 1 < NIT) stage((it + 1) * 32, cur ^ 1);

        bf16x8 a[4], b[4];
        #pragma unroll
        for (int mi = 0; mi < 4; ++mi) {
            int arow = wr * 64 + mi * 16 + l16;
            a[mi] = *(const bf16x8*)&lds[cur][0][arow * 32 + ((lg ^ ((arow >> 1) & 3)) << 3)];
        }
        #pragma unroll
        for (int ni = 0; ni < 4; ++ni) {
            int brow = wc * 64 + ni * 16 + l16;
            b[ni] = *(const bf16x8*)&lds[cur][1][brow * 32 + ((lg ^ ((brow >> 1) & 3)) << 3)];
        }
        #pragma unroll
        for (int mi = 0; mi < 4; ++mi)
            #pragma unroll
            for (int ni = 0; ni < 4; ++ni)
                acc[mi][ni] = __builtin_amdgcn_mfma_f32_16x16x32_bf16(a[mi], b[ni], acc[mi][ni], 0, 0, 0);

        drain_publish();
    }

    const int colblk = n0 + wc * 64;
    if constexpr (MODE == 0) {
        #pragma unroll
        for (int mi = 0; mi < 4; ++mi)
            #pragma unroll
            for (int r = 0; r < 4; ++r) {
                int row = m0 + wr * 64 + mi * 16 + lg * 4 + r;
                #pragma unroll
                for (int ni = 0; ni < 4; ++ni) {
                    int col = colblk + ni * 16 + l16;
                    C[(size_t)row * N + col] = acc[mi][ni][r] + bias[col];
                }
            }
    } else {
        const int which = colblk >> 10;            // 0:q 1:k 2:v (uniform per wave)
        const int e0    = colblk & (E - 1);
        const int h_    = e0 >> 6;
        const int rowg0 = m0 + wr * 64;
        const int b_    = rowg0 >> 11;
        const int s0g   = rowg0 & (S - 1);

        if (which < 2) {
            unsigned short* dst = (which == 0) ? qd : kd;
            const float osc = (which == 0) ? 0.125f * LOG2E : 1.0f;   // fold scale into q
            #pragma unroll
            for (int mi = 0; mi < 4; ++mi)
                #pragma unroll
                for (int r = 0; r < 4; ++r) {
                    int s_ = s0g + mi * 16 + lg * 4 + r;
                    #pragma unroll
                    for (int ni = 0; ni < 4; ++ni) {
                        int col = colblk + ni * 16 + l16;
                        int d_  = col & 63;
                        dst[(((size_t)(b_ * H + h_)) * S + s_) * D + d_] =
                            f2bf((acc[mi][ni][r] + bias[col]) * osc);
                    }
                }
        } else {
            // v: wave-private 4KB repack (2 passes of [32 d][64 s]) -> int4 stores
            unsigned short* et = &lds[0][0][0] + wid * 2048;
            #pragma unroll
            for (int p = 0; p < 2; ++p) {
                #pragma unroll
                for (int nj = 0; nj < 2; ++nj) {
                    int ni   = p * 2 + nj;
                    int dloc = nj * 16 + l16;              // 0..31
                    float bv = bias[colblk + ni * 16 + l16];
                    #pragma unroll
                    for (int mi = 0; mi < 4; ++mi)
                        #pragma unroll
                        for (int r = 0; r < 4; ++r) {
                            int s = mi * 16 + lg * 4 + r;
                            et[dloc * 64 + (((s >> 3) ^ (dloc & 7)) << 3) + (s & 7)] =
                                f2bf(acc[mi][ni][r] + bv);
                        }
                }
                #pragma unroll
                for (int it = 0; it < 4; ++it) {
                    int c  = it * 64 + lane;
                    int dd = c >> 3, j8 = c & 7;
                    int4 vv = *(const int4*)&et[dd * 64 + ((j8 ^ (dd & 7)) << 3)];
                    *(int4*)&vd[(((size_t)(b_ * H + h_)) * D + p * 32 + dd) * S + s0g + j8 * 8] = vv;
                }
            }
        }
    }
}

// ---------------------------------------------------------------------------
// MFMA flash attention, softmax-without-max (R13 structure) with DMA staging:
// K/V tiles staged via global_load_lds (wave-uniform base + lane*16, source
// pre-swizzled) + explicit vmcnt(0)+sched_barrier drain before the publishing
// barrier — the R10-proven race-safe pattern. Removes the VGPR round-trip and
// 4 ds_write issue slots per thread per tile vs reg pass-through staging.
// Everything else identical to R13 (best attn: 160 us).
// ---------------------------------------------------------------------------
__global__ __launch_bounds__(256)
void attn_mfma(const unsigned short* __restrict__ Qb,
               const unsigned short* __restrict__ Kb,
               const unsigned short* __restrict__ Vtb,
               const float* __restrict__ rel,
               unsigned short* __restrict__ AOb)
{
    __shared__ __align__(16) unsigned short lds_k[4096];   // K  [64 k][64 d] swz
    __shared__ __align__(16) unsigned short lds_v[4096];   // Vt [64 d][64 k] swz
    __shared__ unsigned short lds_p[4][1024];              // per-wave P swz

    const int t    = threadIdx.x;
    const int wid  = t >> 6, lane = t & 63;
    const int l16  = lane & 15, lg = lane >> 4;
    const int bh   = blockIdx.y;
    const int q0   = blockIdx.x * 64;
    const int b_   = bh >> 4, h_ = bh & 15;

    const size_t qkoff = (size_t)bh * S * D;
    const size_t vtoff = (size_t)bh * D * S;

    bf16x8 qf[2];   // pre-scaled by 0.125*log2e in gemm_bf16<1>
    {
        const unsigned short* qrow = Qb + qkoff + (size_t)(q0 + wid * 16 + l16) * D;
        qf[0] = *(const bf16x8*)(qrow + lg * 8);
        qf[1] = *(const bf16x8*)(qrow + 32 + lg * 8);
    }

    float l_run[4] = {0.f, 0.f, 0.f, 0.f};
    f32x4 o[4];
    #pragma unroll
    for (int dt = 0; dt < 4; ++dt) o[dt] = (f32x4){0.f, 0.f, 0.f, 0.f};

    for (int k0 = 0; k0 < S; k0 += 64) {
        __syncthreads();   // prev tile's LDS reads complete
        // DMA staging: per wave, chunks [wid*128, wid*128+128) split over 2 issues
        #pragma unroll
        for (int i = 0; i < 2; ++i) {
            int cb  = wid * 128 + i * 64;        // wave-uniform chunk base
            int cl  = cb + lane;                 // this lane's chunk
            int row = cl >> 3, cc = cl & 7;
            int sc  = cc ^ (row & 7);            // pre-swizzled source chunk
            gld_lds16(Kb  + qkoff + (size_t)(k0 + row) * D + sc * 8, &lds_k[cb * 8]);
            gld_lds16(Vtb + vtoff + (size_t)row * S + k0 + sc * 8,   &lds_v[cb * 8]);
        }
        drain_publish();   // vmcnt(0) + sched_barrier + __syncthreads

        // ---- QK^T (pre-scaled) ----
        f32x4 acc[4];
        #pragma unroll
        for (int kt = 0; kt < 4; ++kt) acc[kt] = (f32x4){0.f, 0.f, 0.f, 0.f};
        #pragma unroll
        for (int f = 0; f < 2; ++f) {
            #pragma unroll
            for (int kt = 0; kt < 4; ++kt) {
                int key   = kt * 16 + l16;
                int chunk = (f * 4 + lg) ^ (key & 7);
                bf16x8 kf = *(const bf16x8*)&lds_k[key * 64 + chunk * 8];
                acc[kt] = __builtin_amdgcn_mfma_f32_16x16x32_bf16(qf[f], kf, acc[kt], 0, 0, 0);
            }
        }

        // ---- p = exp2(qk2 + rel*log2e); no max, no rescale ----
        const float* relbase = rel + (size_t)(q0 + wid * 16) * S + k0;
        unsigned short* pw = &lds_p[wid][0];
        #pragma unroll
        for (int kt = 0; kt < 4; ++kt) {
            #pragma unroll
            for (int r = 0; r < 4; ++r) {
                float relv = relbase[(size_t)(lg * 4 + r) * S + kt * 16 + l16];
                float pv = __builtin_amdgcn_exp2f(fmaf(relv, LOG2E, acc[kt][r]));
                l_run[r] += pv;
                int qr = lg * 4 + r;
                int k  = kt * 16 + l16;
                pw[qr * 64 + (((k >> 3) ^ (qr & 7)) << 3) + (k & 7)] = f2bf_fast(pv);
            }
        }

        // ---- PV ----
        #pragma unroll
        for (int f = 0; f < 2; ++f) {
            int pchunk = (f * 4 + lg) ^ (l16 & 7);
            bf16x8 pf = *(const bf16x8*)&pw[l16 * 64 + pchunk * 8];
            #pragma unroll
            for (int dt = 0; dt < 4; ++dt) {
                int d      = dt * 16 + l16;
                int vchunk = (f * 4 + lg) ^ (d & 7);
                bf16x8 vf  = *(const bf16x8*)&lds_v[d * 64 + vchunk * 8];
                o[dt] = __builtin_amdgcn_mfma_f32_16x16x32_bf16(pf, vf, o[dt], 0, 0, 0);
            }
        }
    }

    #pragma unroll
    for (int r = 0; r < 4; ++r) {
        float v = l_run[r];
        v += __shfl_xor(v, 1);
        v += __shfl_xor(v, 2);
        v += __shfl_xor(v, 4);
        v += __shfl_xor(v, 8);
        l_run[r] = v;
    }

    #pragma unroll
    for (int r = 0; r < 4; ++r) {
        float inv = 1.f / l_run[r];
        int qr = q0 + wid * 16 + lg * 4 + r;
        size_t base = ((size_t)b_ * S + qr) * E + h_ * 64;
        #pragma unroll
        for (int dt = 0; dt < 4; ++dt)
            AOb[base + dt * 16 + l16] = f2bf(o[dt][r] * inv);
    }
}

// ---------------------------------------------------------------------------
extern "C" void kernel_launch(void* const* d_in, const int* in_sizes, int n_in,
                              void* d_out, int out_size, void* d_ws, size_t ws_size,
                              hipStream_t stream)
{
    const float* x   = (const float*)d_in[0];
    const float* w1  = (const float*)d_in[1];
    const float* b1  = (const float*)d_in[2];
    const float* w2  = (const float*)d_in[3];
    const float* b2  = (const float*)d_in[4];
    const float* rel = (const float*)d_in[5];
    float* out = (float*)d_out;

    // workspace (ushort), ~76 MiB; AO reuses the xb region (serial stream)
    unsigned short* p = (unsigned short*)d_ws;
    unsigned short* xb  = p;  p += (size_t)M_ROWS * E;    // 16 MiB [8192][1024]
    unsigned short* w1b = p;  p += (size_t)3 * E * E;     //  6 MiB [3072][1024]
    unsigned short* w2b = p;  p += (size_t)E * E;         //  2 MiB [1024][1024]
    unsigned short* qb  = p;  p += (size_t)B * H * S * D; // 16 MiB [B,H,S,D]
    unsigned short* kb  = p;  p += (size_t)B * H * S * D; // 16 MiB [B,H,S,D]
    unsigned short* vb  = p;                              // 16 MiB [B,H,D,S]
    unsigned short* AOb = xb;                             // reuse after gemm<1>

    cvt_bf16<<<dim3(6144), dim3(256), 0, stream>>>(x, xb, w1, w1b, w2, w2b);

    dim3 g1(3 * E / 128, M_ROWS / 128);
    gemm_bf16<1, 1024><<<g1, dim3(256), 0, stream>>>(xb, w1b, b1, nullptr,
                                                     qb, kb, vb, M_ROWS, 3 * E);

    dim3 g2(S / 64, B * H);
    attn_mfma<<<g2, dim3(256), 0, stream>>>(qb, kb, vb, rel, AOb);

    dim3 g3(E / 128, M_ROWS / 128);
    gemm_bf16<0, 1024><<<g3, dim3(256), 0, stream>>>(AOb, w2b, b2, out,
                                                     nullptr, nullptr, nullptr, M_ROWS, E);
}